// Round 8
// baseline (99.982 us; speedup 1.0000x reference)
//
#include <hip/hip_runtime.h>

// GNN layer: deg-normalized aggregation -> Linear+ReLU -> LayerNorm
// N=10000, E=640000, D=128. 4 dispatches:
//  D1 hist_pack:  256-block LDS packed histogram + per-edge ranks;
//                 also packs Hb=bf16x2(H) and WbT=bf16x2(W) transposed.
//  D2 colscan:    8 lanes/bin shfl-combined block-prefix scan (in place),
//                 in-degree cnt, dinv = 1/(outdeg+1).
//  D3 fill:       padded-CSR edge records rec = src | bf16(dinv[src])<<16.
//  D4 aggmmln:    per wave: gather-accumulate 4 node rows (bf16 msgs, fp32
//                 acc) -> stage rows in per-wave LDS -> matmul vs global
//                 WbT (L1-resident) + bias + ReLU + LayerNorm -> out.
// No global atomics, no grid barriers (R6 falsified: contended barrier RMWs
// ~25-35us each), no inter-kernel Hagg round-trip.

#define DFEAT 128
#define MAXN 10240
#define NBLK 256     // histogram partitions
#define PAD 160      // CSR slots/node (mean in-deg 64, max ~102; guarded)
#define SPLIT 8
#define KPT (NBLK / SPLIT)  // 32 hist-blocks per colscan lane

__device__ __forceinline__ unsigned bf16rne(float f) {
    unsigned u = __float_as_uint(f);
    return (u + 0x7fffu + ((u >> 16) & 1u)) >> 16;
}
__device__ __forceinline__ float bflo(unsigned u) { return __uint_as_float(u << 16); }
__device__ __forceinline__ float bfhi(unsigned u) { return __uint_as_float(u & 0xffff0000u); }

// D1: packed per-block histogram (low16=source/out-deg, high16=dest/in-deg;
// Epb=2500 so no carry), per-edge dest ranks; plus bf16 packing side-work.
__global__ __launch_bounds__(1024) void hist_pack_kernel(
    const int* __restrict__ ei, int E, int Epb, int N,
    const float* __restrict__ H, const float* __restrict__ W,
    int* __restrict__ packedHist, unsigned short* __restrict__ rank16,
    unsigned* __restrict__ Hb, unsigned* __restrict__ WbT) {
    __shared__ unsigned h[MAXN];
    int t = threadIdx.x, b = blockIdx.x;
    for (int i = t; i < N; i += 1024) h[i] = 0u;
    __syncthreads();
    {
        int e0 = b * Epb, e1 = min(E, e0 + Epb);
        for (int e = e0 + t; e < e1; e += 1024) {
            atomicAdd(&h[ei[e]], 1u);                               // source
            unsigned old = atomicAdd(&h[ei[E + e]], 0x10000u);      // dest
            rank16[e] = (unsigned short)(old >> 16);
        }
    }
    __syncthreads();
    for (int i = t; i < N; i += 1024) packedHist[b * N + i] = (int)h[i];
    // side-work A: Hb = bf16x2(H)  (dinv applied later via edge records)
    {
        const float2* __restrict__ H2 = (const float2*)H;
        int total = N * (DFEAT / 2);
        for (int i = b * 1024 + t; i < total; i += NBLK * 1024) {
            float2 hh = H2[i];
            Hb[i] = bf16rne(hh.x) | (bf16rne(hh.y) << 16);
        }
    }
    // side-work B: WbT[k2*128+d] = bf16x2(W[d][2k2], W[d][2k2+1])
    {
        int gid = b * 1024 + t;
        if (gid < 128 * (DFEAT / 2)) {
            int k2 = gid >> 7, d = gid & 127;
            WbT[gid] = bf16rne(W[d * 128 + 2 * k2]) |
                       (bf16rne(W[d * 128 + 2 * k2 + 1]) << 16);
        }
    }
}

// D2: per-bin, 8 lanes each scan 32 hist-blocks; shfl-combine across the
// 8-lane group; write exclusive prefixes back in place (2-pass, low VGPR).
__global__ __launch_bounds__(256) void colscan_kernel(
    int* __restrict__ packedHist, float* __restrict__ dinv,
    int* __restrict__ cnt, int N) {
    int tid = blockIdx.x * 256 + threadIdx.x;
    int b = tid >> 3, p = tid & 7;
    if (b >= N) return;  // whole 8-lane groups drop together
    int lane = threadIdx.x & 63;
    int base = p * KPT;
    int sR = 0, sC = 0;
#pragma unroll
    for (int j = 0; j < KPT; ++j) {
        unsigned v = (unsigned)packedHist[(base + j) * N + b];
        sR += (int)(v & 0xffffu);
        sC += (int)(v >> 16);
    }
    int incl = sC;
    int u1 = __shfl_up(incl, 1); if (p >= 1) incl += u1;
    int u2 = __shfl_up(incl, 2); if (p >= 2) incl += u2;
    int u4 = __shfl_up(incl, 4); if (p >= 4) incl += u4;
    int gExcl = incl - sC;
    int totC = __shfl(incl, lane | 7);  // group's last lane = total in-deg
    int tR = sR;
    tR += __shfl_xor(tR, 1);
    tR += __shfl_xor(tR, 2);
    tR += __shfl_xor(tR, 4);
    int run = gExcl;
#pragma unroll
    for (int j = 0; j < KPT; ++j) {
        unsigned v = (unsigned)packedHist[(base + j) * N + b];
        packedHist[(base + j) * N + b] = run;
        run += (int)(v >> 16);
    }
    if (p == 0) {
        dinv[b] = 1.0f / (float)(tR + 1);  // +1 self-loop
        cnt[b] = min(totC, PAD);
    }
}

// D3: padded-CSR fill, stateless; record = src | bf16(dinv[src])<<16.
__global__ __launch_bounds__(256) void fill_kernel(
    const int* __restrict__ ei, int E, int Epb, int N,
    const int* __restrict__ blkpref, const unsigned short* __restrict__ rank16,
    const float* __restrict__ dinv, unsigned* __restrict__ edge_rec,
    int subPerBlk) {
    int b = blockIdx.x / subPerBlk;   // hist partition (block-uniform)
    int sub = blockIdx.x - b * subPerBlk;
    int e0 = b * Epb, e1 = min(E, e0 + Epb);
    const int* __restrict__ pre = blkpref + b * N;
    int stride = subPerBlk * 256;
    for (int e = e0 + sub * 256 + threadIdx.x; e < e1; e += stride) {
        int c = ei[E + e];
        int slot = pre[c] + (int)rank16[e];
        if (slot < PAD) {  // statistically impossible; keeps memory safe
            int s = ei[e];
            edge_rec[c * PAD + slot] = (unsigned)s | (bf16rne(dinv[s]) << 16);
        }
    }
}

// D4: fused aggregate + matmul + bias + ReLU + LayerNorm.
// 4 waves/block, 4 nodes/wave. Gather: bf16 rows * bf16 weights, fp32 acc.
// Rows staged in per-wave-private LDS (no cross-wave sync needed; wave-local
// ds_write->ds_read ordered via lgkmcnt(0) + sched_barrier, guide rule 18).
// W read from global WbT (32KB, L1-resident).
__global__ __launch_bounds__(256) void aggmmln_kernel(
    const unsigned* __restrict__ Hb, const unsigned* __restrict__ WbT,
    const int* __restrict__ cnt, const unsigned* __restrict__ edge_rec,
    const float* __restrict__ dinv, const float* __restrict__ bias,
    const float* __restrict__ gamma, const float* __restrict__ beta,
    float* __restrict__ out, int N) {
    __shared__ float rows[4][4][DFEAT];  // 8 KB, per-wave-private slices
    int t = threadIdx.x;
    int w = t >> 6, l = t & 63;
    int base = (blockIdx.x * 4 + w) * 4;

    // ---- gather 4 node rows ----
#pragma unroll
    for (int j = 0; j < 4; ++j) {
        int c = base + j;
        float x = 0.f, y = 0.f;
        if (c < N) {
            unsigned su = Hb[c * 64 + l];
            float wc = dinv[c];
            x = bflo(su) * wc;  // self message, fp32 weight
            y = bfhi(su) * wc;
            int deg = cnt[c];
            const unsigned* __restrict__ er = edge_rec + c * PAD;  // 16B-aligned
            int e = 0;
            for (; e + 4 <= deg; e += 4) {
                uint4 rv = *(const uint4*)(er + e);  // 4 edge records
                unsigned s0 = rv.x & 0xffffu; float w0 = bfhi(rv.x);
                unsigned s1 = rv.y & 0xffffu; float w1 = bfhi(rv.y);
                unsigned s2 = rv.z & 0xffffu; float w2 = bfhi(rv.z);
                unsigned s3 = rv.w & 0xffffu; float w3 = bfhi(rv.w);
                unsigned u0 = Hb[s0 * 64 + l], u1c = Hb[s1 * 64 + l];
                unsigned u2c = Hb[s2 * 64 + l], u3 = Hb[s3 * 64 + l];
                x += bflo(u0) * w0 + bflo(u1c) * w1 + bflo(u2c) * w2 + bflo(u3) * w3;
                y += bfhi(u0) * w0 + bfhi(u1c) * w1 + bfhi(u2c) * w2 + bfhi(u3) * w3;
            }
            for (; e < deg; ++e) {
                unsigned rv = er[e];
                unsigned s = rv & 0xffffu;
                float ww = bfhi(rv);
                unsigned u = Hb[s * 64 + l];
                x += bflo(u) * ww;
                y += bfhi(u) * ww;
            }
        }
        *(float2*)&rows[w][j][2 * l] = make_float2(x, y);
    }
    asm volatile("s_waitcnt lgkmcnt(0)" ::: "memory");
    __builtin_amdgcn_sched_barrier(0);

    // ---- matmul + bias + ReLU + LN ----
    float b0 = bias[l], b1 = bias[l + 64];
    float g0 = gamma[l], g1 = gamma[l + 64];
    float be0 = beta[l], be1 = beta[l + 64];
    float a0[4], a1[4];
#pragma unroll
    for (int j = 0; j < 4; ++j) { a0[j] = b0; a1[j] = b1; }
#pragma unroll 4
    for (int k2 = 0; k2 < 64; ++k2) {
        unsigned wA = WbT[k2 * 128 + l];        // W[l][2k2], W[l][2k2+1]
        unsigned wB = WbT[k2 * 128 + l + 64];   // W[l+64][...]
        float wA0 = bflo(wA), wA1 = bfhi(wA);
        float wB0 = bflo(wB), wB1 = bfhi(wB);
#pragma unroll
        for (int j = 0; j < 4; ++j) {
            float2 xv = *(const float2*)&rows[w][j][2 * k2];  // broadcast read
            a0[j] += xv.x * wA0 + xv.y * wA1;
            a1[j] += xv.x * wB0 + xv.y * wB1;
        }
    }
#pragma unroll
    for (int j = 0; j < 4; ++j) {
        int c = base + j;
        if (c >= N) continue;
        float v0 = fmaxf(a0[j], 0.f), v1 = fmaxf(a1[j], 0.f);
        float s = v0 + v1, q = v0 * v0 + v1 * v1;
        for (int o = 32; o; o >>= 1) {
            s += __shfl_xor(s, o);
            q += __shfl_xor(q, o);
        }
        float mean = s * (1.0f / 128.0f);
        float var = q * (1.0f / 128.0f) - mean * mean;
        float rstd = rsqrtf(var + 1e-5f);
        out[(size_t)c * 128 + l] = (v0 - mean) * rstd * g0 + be0;
        out[(size_t)c * 128 + l + 64] = (v1 - mean) * rstd * g1 + be1;
    }
}

extern "C" void kernel_launch(void* const* d_in, const int* in_sizes, int n_in,
                              void* d_out, int out_size, void* d_ws, size_t ws_size,
                              hipStream_t stream) {
    const float* H = (const float*)d_in[0];
    const int* ei = (const int*)d_in[1];
    const float* W = (const float*)d_in[3];
    const float* bias = (const float*)d_in[4];
    const float* gamma = (const float*)d_in[5];
    const float* beta = (const float*)d_in[6];
    float* out = (float*)d_out;

    const int N = in_sizes[0] / DFEAT;  // 10000 (<= MAXN)
    const int E = in_sizes[1] / 2;      // 640000
    const int Epb = (E + NBLK - 1) / NBLK;  // 2500

    char* wp = (char*)d_ws;
    auto alloc = [&](size_t bytes) {
        char* p = wp;
        wp += (bytes + 255) & ~(size_t)255;
        return p;
    };
    int* packedHist = (int*)alloc((size_t)NBLK * N * 4);             // 10.24 MB
    unsigned short* rank16 = (unsigned short*)alloc((size_t)E * 2);  // 1.28 MB
    unsigned* edge_rec = (unsigned*)alloc((size_t)N * PAD * 4);      // 6.4 MB
    unsigned* Hb = (unsigned*)alloc((size_t)N * (DFEAT / 2) * 4);    // 2.56 MB
    unsigned* WbT = (unsigned*)alloc((size_t)128 * (DFEAT / 2) * 4); // 32 KB
    int* cnt = (int*)alloc((size_t)N * 4);
    float* dinv = (float*)alloc((size_t)N * 4);
    (void)ws_size;

    hist_pack_kernel<<<NBLK, 1024, 0, stream>>>(ei, E, Epb, N, H, W,
                                                packedHist, rank16, Hb, WbT);
    colscan_kernel<<<(N * SPLIT + 255) / 256, 256, 0, stream>>>(
        packedHist, dinv, cnt, N);
    {
        int subPerBlk = 4;  // grid = 1024 blocks
        fill_kernel<<<NBLK * subPerBlk, 256, 0, stream>>>(
            ei, E, Epb, N, packedHist, rank16, dinv, edge_rec, subPerBlk);
    }
    aggmmln_kernel<<<(N + 15) / 16, 256, 0, stream>>>(
        Hb, WbT, cnt, edge_rec, dinv, bias, gamma, beta, out, N);
}

// Round 9
// 79.070 us; speedup vs baseline: 1.2645x; 1.2645x over previous
//
#include <hip/hip_runtime.h>

// GNN layer: deg-normalized aggregation -> Linear+ReLU -> LayerNorm
// N=10000, E=640000, D=128. 4 dispatches:
//  D1 hist_pack:  256-block LDS packed histogram + per-edge ranks;
//                 also packs Hb=bf16x2(H) and WbT=bf16x2(W) transposed.
//  D2 colscan:    8 lanes/bin shfl-combined block-prefix scan (in place),
//                 in-degree cnt, dinv = 1/(outdeg+1).
//  D3 fill:       padded-CSR edge records rec = src | bf16(dinv[src])<<16.
//  D4 aggmmln:    ONE NODE PER WAVE (R8's 4-nodes/wave starved the gather
//                 of parallelism: 20% occupancy, 52us). Wave gathers its
//                 row (bf16 msgs, fp32 acc, 8-edge unroll), stages 512B in
//                 private LDS, then computes the node's matmul vs global
//                 WbT (L1-resident) + bias + ReLU + LayerNorm.

#define DFEAT 128
#define MAXN 10240
#define NBLK 256     // histogram partitions
#define PAD 160      // CSR slots/node (mean in-deg 64, max ~102; guarded)
#define SPLIT 8
#define KPT (NBLK / SPLIT)  // 32 hist-blocks per colscan lane

__device__ __forceinline__ unsigned bf16rne(float f) {
    unsigned u = __float_as_uint(f);
    return (u + 0x7fffu + ((u >> 16) & 1u)) >> 16;
}
__device__ __forceinline__ float bflo(unsigned u) { return __uint_as_float(u << 16); }
__device__ __forceinline__ float bfhi(unsigned u) { return __uint_as_float(u & 0xffff0000u); }

// D1: packed per-block histogram (low16=source/out-deg, high16=dest/in-deg;
// Epb=2500 so no carry), per-edge dest ranks; plus bf16 packing side-work.
__global__ __launch_bounds__(1024) void hist_pack_kernel(
    const int* __restrict__ ei, int E, int Epb, int N,
    const float* __restrict__ H, const float* __restrict__ W,
    int* __restrict__ packedHist, unsigned short* __restrict__ rank16,
    unsigned* __restrict__ Hb, unsigned* __restrict__ WbT) {
    __shared__ unsigned h[MAXN];
    int t = threadIdx.x, b = blockIdx.x;
    for (int i = t; i < N; i += 1024) h[i] = 0u;
    __syncthreads();
    {
        int e0 = b * Epb, e1 = min(E, e0 + Epb);
        for (int e = e0 + t; e < e1; e += 1024) {
            atomicAdd(&h[ei[e]], 1u);                               // source
            unsigned old = atomicAdd(&h[ei[E + e]], 0x10000u);      // dest
            rank16[e] = (unsigned short)(old >> 16);
        }
    }
    __syncthreads();
    for (int i = t; i < N; i += 1024) packedHist[b * N + i] = (int)h[i];
    // side-work A: Hb = bf16x2(H)  (dinv applied later via edge records)
    {
        const float2* __restrict__ H2 = (const float2*)H;
        int total = N * (DFEAT / 2);
        for (int i = b * 1024 + t; i < total; i += NBLK * 1024) {
            float2 hh = H2[i];
            Hb[i] = bf16rne(hh.x) | (bf16rne(hh.y) << 16);
        }
    }
    // side-work B: WbT[k2*128+d] = bf16x2(W[d][2k2], W[d][2k2+1])
    {
        int gid = b * 1024 + t;
        if (gid < 128 * (DFEAT / 2)) {
            int k2 = gid >> 7, d = gid & 127;
            WbT[gid] = bf16rne(W[d * 128 + 2 * k2]) |
                       (bf16rne(W[d * 128 + 2 * k2 + 1]) << 16);
        }
    }
}

// D2: per-bin, 8 lanes each scan 32 hist-blocks; shfl-combine across the
// 8-lane group; write exclusive prefixes back in place (2-pass, low VGPR).
__global__ __launch_bounds__(256) void colscan_kernel(
    int* __restrict__ packedHist, float* __restrict__ dinv,
    int* __restrict__ cnt, int N) {
    int tid = blockIdx.x * 256 + threadIdx.x;
    int b = tid >> 3, p = tid & 7;
    if (b >= N) return;  // whole 8-lane groups drop together
    int lane = threadIdx.x & 63;
    int base = p * KPT;
    int sR = 0, sC = 0;
#pragma unroll
    for (int j = 0; j < KPT; ++j) {
        unsigned v = (unsigned)packedHist[(base + j) * N + b];
        sR += (int)(v & 0xffffu);
        sC += (int)(v >> 16);
    }
    int incl = sC;
    int u1 = __shfl_up(incl, 1); if (p >= 1) incl += u1;
    int u2 = __shfl_up(incl, 2); if (p >= 2) incl += u2;
    int u4 = __shfl_up(incl, 4); if (p >= 4) incl += u4;
    int gExcl = incl - sC;
    int totC = __shfl(incl, lane | 7);  // group's last lane = total in-deg
    int tR = sR;
    tR += __shfl_xor(tR, 1);
    tR += __shfl_xor(tR, 2);
    tR += __shfl_xor(tR, 4);
    int run = gExcl;
#pragma unroll
    for (int j = 0; j < KPT; ++j) {
        unsigned v = (unsigned)packedHist[(base + j) * N + b];
        packedHist[(base + j) * N + b] = run;
        run += (int)(v >> 16);
    }
    if (p == 0) {
        dinv[b] = 1.0f / (float)(tR + 1);  // +1 self-loop
        cnt[b] = min(totC, PAD);
    }
}

// D3: padded-CSR fill, stateless; record = src | bf16(dinv[src])<<16.
__global__ __launch_bounds__(256) void fill_kernel(
    const int* __restrict__ ei, int E, int Epb, int N,
    const int* __restrict__ blkpref, const unsigned short* __restrict__ rank16,
    const float* __restrict__ dinv, unsigned* __restrict__ edge_rec,
    int subPerBlk) {
    int b = blockIdx.x / subPerBlk;   // hist partition (block-uniform)
    int sub = blockIdx.x - b * subPerBlk;
    int e0 = b * Epb, e1 = min(E, e0 + Epb);
    const int* __restrict__ pre = blkpref + b * N;
    int stride = subPerBlk * 256;
    for (int e = e0 + sub * 256 + threadIdx.x; e < e1; e += stride) {
        int c = ei[E + e];
        int slot = pre[c] + (int)rank16[e];
        if (slot < PAD) {  // statistically impossible; keeps memory safe
            int s = ei[e];
            edge_rec[c * PAD + slot] = (unsigned)s | (bf16rne(dinv[s]) << 16);
        }
    }
}

// D4: fused aggregate + matmul + bias + ReLU + LayerNorm. ONE node per wave
// (grid N/4 x 4 waves -> 10000 waves for latency hiding). Row staged in
// per-wave-private LDS (wave-local ds ordering via lgkmcnt+sched_barrier).
__global__ __launch_bounds__(256) void aggmmln_kernel(
    const unsigned* __restrict__ Hb, const unsigned* __restrict__ WbT,
    const int* __restrict__ cnt, const unsigned* __restrict__ edge_rec,
    const float* __restrict__ dinv, const float* __restrict__ bias,
    const float* __restrict__ gamma, const float* __restrict__ beta,
    float* __restrict__ out, int N) {
    __shared__ float rows[4][DFEAT];  // 2 KB, one row per wave
    int t = threadIdx.x;
    int w = t >> 6, l = t & 63;
    int c = blockIdx.x * 4 + w;

    // ---- gather this wave's node row (fp32 acc, bf16 msgs) ----
    float x = 0.f, y = 0.f;
    if (c < N) {
        unsigned su = Hb[c * 64 + l];
        float wc = dinv[c];
        x = bflo(su) * wc;  // self message
        y = bfhi(su) * wc;
        int deg = cnt[c];
        const unsigned* __restrict__ er = edge_rec + c * PAD;  // 16B-aligned
        int e = 0;
        for (; e + 8 <= deg; e += 8) {
            uint4 ra = *(const uint4*)(er + e);
            uint4 rb = *(const uint4*)(er + e + 4);
            unsigned s0 = ra.x & 0xffffu; float w0 = bfhi(ra.x);
            unsigned s1 = ra.y & 0xffffu; float w1 = bfhi(ra.y);
            unsigned s2 = ra.z & 0xffffu; float w2 = bfhi(ra.z);
            unsigned s3 = ra.w & 0xffffu; float w3 = bfhi(ra.w);
            unsigned s4 = rb.x & 0xffffu; float w4 = bfhi(rb.x);
            unsigned s5 = rb.y & 0xffffu; float w5 = bfhi(rb.y);
            unsigned s6 = rb.z & 0xffffu; float w6 = bfhi(rb.z);
            unsigned s7 = rb.w & 0xffffu; float w7 = bfhi(rb.w);
            unsigned u0 = Hb[s0 * 64 + l], u1 = Hb[s1 * 64 + l];
            unsigned u2 = Hb[s2 * 64 + l], u3 = Hb[s3 * 64 + l];
            unsigned u4 = Hb[s4 * 64 + l], u5 = Hb[s5 * 64 + l];
            unsigned u6 = Hb[s6 * 64 + l], u7 = Hb[s7 * 64 + l];
            x += bflo(u0) * w0 + bflo(u1) * w1 + bflo(u2) * w2 + bflo(u3) * w3 +
                 bflo(u4) * w4 + bflo(u5) * w5 + bflo(u6) * w6 + bflo(u7) * w7;
            y += bfhi(u0) * w0 + bfhi(u1) * w1 + bfhi(u2) * w2 + bfhi(u3) * w3 +
                 bfhi(u4) * w4 + bfhi(u5) * w5 + bfhi(u6) * w6 + bfhi(u7) * w7;
        }
        for (; e < deg; ++e) {
            unsigned rv = er[e];
            unsigned s = rv & 0xffffu;
            float ww = bfhi(rv);
            unsigned u = Hb[s * 64 + l];
            x += bflo(u) * ww;
            y += bfhi(u) * ww;
        }
    }
    *(float2*)&rows[w][2 * l] = make_float2(x, y);
    asm volatile("s_waitcnt lgkmcnt(0)" ::: "memory");
    __builtin_amdgcn_sched_barrier(0);

    // ---- matmul (this wave's node) + bias + ReLU + LN ----
    float a0 = bias[l], a1 = bias[l + 64];
#pragma unroll 8
    for (int k2 = 0; k2 < 64; ++k2) {
        unsigned wA = WbT[k2 * 128 + l];        // W[l][2k2..]
        unsigned wB = WbT[k2 * 128 + l + 64];   // W[l+64][2k2..]
        float2 xv = *(const float2*)&rows[w][2 * k2];  // broadcast read
        a0 += xv.x * bflo(wA) + xv.y * bfhi(wA);
        a1 += xv.x * bflo(wB) + xv.y * bfhi(wB);
    }
    float v0 = fmaxf(a0, 0.f), v1 = fmaxf(a1, 0.f);
    float s = v0 + v1, q = v0 * v0 + v1 * v1;
    for (int o = 32; o; o >>= 1) {
        s += __shfl_xor(s, o);
        q += __shfl_xor(q, o);
    }
    float mean = s * (1.0f / 128.0f);
    float var = q * (1.0f / 128.0f) - mean * mean;
    float rstd = rsqrtf(var + 1e-5f);
    if (c < N) {
        out[(size_t)c * 128 + l] = (v0 - mean) * rstd * gamma[l] + beta[l];
        out[(size_t)c * 128 + l + 64] =
            (v1 - mean) * rstd * gamma[l + 64] + beta[l + 64];
    }
}

extern "C" void kernel_launch(void* const* d_in, const int* in_sizes, int n_in,
                              void* d_out, int out_size, void* d_ws, size_t ws_size,
                              hipStream_t stream) {
    const float* H = (const float*)d_in[0];
    const int* ei = (const int*)d_in[1];
    const float* W = (const float*)d_in[3];
    const float* bias = (const float*)d_in[4];
    const float* gamma = (const float*)d_in[5];
    const float* beta = (const float*)d_in[6];
    float* out = (float*)d_out;

    const int N = in_sizes[0] / DFEAT;  // 10000 (<= MAXN)
    const int E = in_sizes[1] / 2;      // 640000
    const int Epb = (E + NBLK - 1) / NBLK;  // 2500

    char* wp = (char*)d_ws;
    auto alloc = [&](size_t bytes) {
        char* p = wp;
        wp += (bytes + 255) & ~(size_t)255;
        return p;
    };
    int* packedHist = (int*)alloc((size_t)NBLK * N * 4);             // 10.24 MB
    unsigned short* rank16 = (unsigned short*)alloc((size_t)E * 2);  // 1.28 MB
    unsigned* edge_rec = (unsigned*)alloc((size_t)N * PAD * 4);      // 6.4 MB
    unsigned* Hb = (unsigned*)alloc((size_t)N * (DFEAT / 2) * 4);    // 2.56 MB
    unsigned* WbT = (unsigned*)alloc((size_t)128 * (DFEAT / 2) * 4); // 32 KB
    int* cnt = (int*)alloc((size_t)N * 4);
    float* dinv = (float*)alloc((size_t)N * 4);
    (void)ws_size;

    hist_pack_kernel<<<NBLK, 1024, 0, stream>>>(ei, E, Epb, N, H, W,
                                                packedHist, rank16, Hb, WbT);
    colscan_kernel<<<(N * SPLIT + 255) / 256, 256, 0, stream>>>(
        packedHist, dinv, cnt, N);
    {
        int subPerBlk = 4;  // grid = 1024 blocks
        fill_kernel<<<NBLK * subPerBlk, 256, 0, stream>>>(
            ei, E, Epb, N, packedHist, rank16, dinv, edge_rec, subPerBlk);
    }
    aggmmln_kernel<<<(N + 3) / 4, 256, 0, stream>>>(
        Hb, WbT, cnt, edge_rec, dinv, bias, gamma, beta, out, N);
}

// Round 10
// 64.140 us; speedup vs baseline: 1.5588x; 1.2328x over previous
//
#include <hip/hip_runtime.h>

// GNN layer: deg-normalized aggregation -> Linear+ReLU -> LayerNorm
// N=10000, E=640000, D=128. 4 dispatches:
//  D1 hist_pack:  128-block LDS packed histogram + per-edge ranks;
//                 side-work: WbT = bf16x2(W) transposed (no deps).
//  D2 colscan:    8 lanes/bin shfl-combined block-prefix scan (in place),
//                 in-degree cnt (capped PAD), dinv = 1/(outdeg+1).
//  D3 fillscale:  (A) HsU = bf16x2(H * dinv) pre-scale;
//                 (B) padded-CSR fill of u16 src indices (stateless).
//  D4 aggmmln:    one node per wave: gather-add prescaled bf16 rows (fp32
//                 acc, 8-edge unroll), stage row in private LDS, matmul vs
//                 global WbT (L1-resident) + bias + ReLU + LayerNorm.
// Pre-scaled messages (R7-validated, absmax 0.031): gather is pure adds,
// edge records are 2B, fill needs no per-edge dinv load.

#define DFEAT 128
#define MAXN 10240
#define NBLK 128     // histogram partitions
#define PAD 160      // CSR slots/node (mean in-deg 64, max ~102; guarded)
#define SPLIT 8
#define KPT (NBLK / SPLIT)  // 16 hist-blocks per colscan lane

__device__ __forceinline__ unsigned bf16rne(float f) {
    unsigned u = __float_as_uint(f);
    return (u + 0x7fffu + ((u >> 16) & 1u)) >> 16;
}
__device__ __forceinline__ float bflo(unsigned u) { return __uint_as_float(u << 16); }
__device__ __forceinline__ float bfhi(unsigned u) { return __uint_as_float(u & 0xffff0000u); }

// D1: packed per-block histogram (low16=source/out-deg, high16=dest/in-deg;
// Epb=5000 so halves never carry), per-edge dest ranks; WbT pack side-work.
__global__ __launch_bounds__(1024) void hist_pack_kernel(
    const int* __restrict__ ei, int E, int Epb, int N,
    const float* __restrict__ W, int* __restrict__ packedHist,
    unsigned short* __restrict__ rank16, unsigned* __restrict__ WbT) {
    __shared__ unsigned h[MAXN];
    int t = threadIdx.x, b = blockIdx.x;
    for (int i = t; i < N; i += 1024) h[i] = 0u;
    __syncthreads();
    {
        int e0 = b * Epb, e1 = min(E, e0 + Epb);
        for (int e = e0 + t; e < e1; e += 1024) {
            atomicAdd(&h[ei[e]], 1u);                               // source
            unsigned old = atomicAdd(&h[ei[E + e]], 0x10000u);      // dest
            rank16[e] = (unsigned short)(old >> 16);
        }
    }
    __syncthreads();
    for (int i = t; i < N; i += 1024) packedHist[b * N + i] = (int)h[i];
    // side-work: WbT[k2*128+d] = bf16x2(W[d][2k2], W[d][2k2+1])
    {
        int gid = b * 1024 + t;
        if (gid < 128 * (DFEAT / 2)) {
            int k2 = gid >> 7, d = gid & 127;
            WbT[gid] = bf16rne(W[d * 128 + 2 * k2]) |
                       (bf16rne(W[d * 128 + 2 * k2 + 1]) << 16);
        }
    }
}

// D2: per-bin, 8 lanes each scan 16 hist-blocks; shfl-combine across the
// 8-lane group; write exclusive prefixes back in place (2-pass, low VGPR).
__global__ __launch_bounds__(256) void colscan_kernel(
    int* __restrict__ packedHist, float* __restrict__ dinv,
    int* __restrict__ cnt, int N) {
    int tid = blockIdx.x * 256 + threadIdx.x;
    int b = tid >> 3, p = tid & 7;
    if (b >= N) return;  // whole 8-lane groups drop together
    int lane = threadIdx.x & 63;
    int base = p * KPT;
    int sR = 0, sC = 0;
#pragma unroll
    for (int j = 0; j < KPT; ++j) {
        unsigned v = (unsigned)packedHist[(base + j) * N + b];
        sR += (int)(v & 0xffffu);
        sC += (int)(v >> 16);
    }
    int incl = sC;
    int u1 = __shfl_up(incl, 1); if (p >= 1) incl += u1;
    int u2 = __shfl_up(incl, 2); if (p >= 2) incl += u2;
    int u4 = __shfl_up(incl, 4); if (p >= 4) incl += u4;
    int gExcl = incl - sC;
    int totC = __shfl(incl, lane | 7);  // group's last lane = total in-deg
    int tR = sR;
    tR += __shfl_xor(tR, 1);
    tR += __shfl_xor(tR, 2);
    tR += __shfl_xor(tR, 4);
    int run = gExcl;
#pragma unroll
    for (int j = 0; j < KPT; ++j) {
        unsigned v = (unsigned)packedHist[(base + j) * N + b];
        packedHist[(base + j) * N + b] = run;
        run += (int)(v >> 16);
    }
    if (p == 0) {
        dinv[b] = 1.0f / (float)(tR + 1);  // +1 self-loop
        cnt[b] = min(totC, PAD);
    }
}

// D3: (A) HsU = bf16x2(H*dinv) pre-scale (grid-stride);
//     (B) padded-CSR fill of u16 src, hist-partition-aligned, stateless.
__global__ __launch_bounds__(256) void fillscale_kernel(
    const int* __restrict__ ei, int E, int Epb, int N,
    const int* __restrict__ blkpref, const unsigned short* __restrict__ rank16,
    unsigned short* __restrict__ edge_src,
    const float* __restrict__ H, const float* __restrict__ dinv,
    unsigned* __restrict__ HsU, int subPerBlk) {
    // phase A: pre-scale + bf16 pack
    {
        int tid = blockIdx.x * 256 + threadIdx.x;
        int total = N * (DFEAT / 2);
        int stride = gridDim.x * 256;
        const float2* __restrict__ H2 = (const float2*)H;
        for (int i = tid; i < total; i += stride) {
            float d = dinv[i >> 6];
            float2 hh = H2[i];
            HsU[i] = bf16rne(hh.x * d) | (bf16rne(hh.y * d) << 16);
        }
    }
    // phase B: fill (block-uniform hist-partition id)
    int b = blockIdx.x / subPerBlk;
    int sub = blockIdx.x - b * subPerBlk;
    if (b < NBLK) {
        int e0 = b * Epb, e1 = min(E, e0 + Epb);
        const int* __restrict__ pre = blkpref + b * N;
        int stride = subPerBlk * 256;
        for (int e = e0 + sub * 256 + threadIdx.x; e < e1; e += stride) {
            int c = ei[E + e];
            int slot = pre[c] + (int)rank16[e];
            if (slot < PAD)  // statistically impossible; keeps memory safe
                edge_src[c * PAD + slot] = (unsigned short)ei[e];
        }
    }
}

// D4: fused aggregate + matmul + bias + ReLU + LayerNorm. One node per wave
// (10000 waves). Gather = pure adds of prescaled bf16 rows, fp32 acc. Row
// staged in per-wave-private LDS (wave-local ds ordering via lgkmcnt +
// sched_barrier, guide rule 18). W from global WbT (32KB, L1-resident).
__global__ __launch_bounds__(256) void aggmmln_kernel(
    const unsigned* __restrict__ HsU, const unsigned* __restrict__ WbT,
    const int* __restrict__ cnt, const unsigned short* __restrict__ edge_src,
    const float* __restrict__ bias, const float* __restrict__ gamma,
    const float* __restrict__ beta, float* __restrict__ out, int N) {
    __shared__ float rows[4][DFEAT];  // 2 KB, one row per wave
    int t = threadIdx.x;
    int w = t >> 6, l = t & 63;
    int c = blockIdx.x * 4 + w;

    // ---- gather this wave's node row (fp32 acc, prescaled bf16 msgs) ----
    float x = 0.f, y = 0.f;
    if (c < N) {
        unsigned su = HsU[c * 64 + l];  // self message (prescaled)
        x = bflo(su);
        y = bfhi(su);
        int deg = cnt[c];
        const unsigned short* __restrict__ es = edge_src + c * PAD;  // 320B-aligned
        int e = 0;
        for (; e + 8 <= deg; e += 8) {
            uint4 iv = *(const uint4*)(es + e);  // 8 u16 indices
            int s0 = iv.x & 0xffff, s1 = iv.x >> 16;
            int s2 = iv.y & 0xffff, s3 = iv.y >> 16;
            int s4 = iv.z & 0xffff, s5 = iv.z >> 16;
            int s6 = iv.w & 0xffff, s7 = iv.w >> 16;
            unsigned u0 = HsU[s0 * 64 + l], u1 = HsU[s1 * 64 + l];
            unsigned u2 = HsU[s2 * 64 + l], u3 = HsU[s3 * 64 + l];
            unsigned u4 = HsU[s4 * 64 + l], u5 = HsU[s5 * 64 + l];
            unsigned u6 = HsU[s6 * 64 + l], u7 = HsU[s7 * 64 + l];
            x += bflo(u0) + bflo(u1) + bflo(u2) + bflo(u3) +
                 bflo(u4) + bflo(u5) + bflo(u6) + bflo(u7);
            y += bfhi(u0) + bfhi(u1) + bfhi(u2) + bfhi(u3) +
                 bfhi(u4) + bfhi(u5) + bfhi(u6) + bfhi(u7);
        }
        for (; e < deg; ++e) {
            unsigned u = HsU[(int)es[e] * 64 + l];
            x += bflo(u);
            y += bfhi(u);
        }
    }
    *(float2*)&rows[w][2 * l] = make_float2(x, y);
    asm volatile("s_waitcnt lgkmcnt(0)" ::: "memory");
    __builtin_amdgcn_sched_barrier(0);

    // ---- matmul (this wave's node) + bias + ReLU + LN ----
    float a0 = bias[l], a1 = bias[l + 64];
#pragma unroll 8
    for (int k2 = 0; k2 < 64; ++k2) {
        unsigned wA = WbT[k2 * 128 + l];        // W[l][2k2..]
        unsigned wB = WbT[k2 * 128 + l + 64];   // W[l+64][2k2..]
        float2 xv = *(const float2*)&rows[w][2 * k2];  // broadcast read
        a0 += xv.x * bflo(wA) + xv.y * bfhi(wA);
        a1 += xv.x * bflo(wB) + xv.y * bfhi(wB);
    }
    float v0 = fmaxf(a0, 0.f), v1 = fmaxf(a1, 0.f);
    float s = v0 + v1, q = v0 * v0 + v1 * v1;
    for (int o = 32; o; o >>= 1) {
        s += __shfl_xor(s, o);
        q += __shfl_xor(q, o);
    }
    float mean = s * (1.0f / 128.0f);
    float var = q * (1.0f / 128.0f) - mean * mean;
    float rstd = rsqrtf(var + 1e-5f);
    if (c < N) {
        out[(size_t)c * 128 + l] = (v0 - mean) * rstd * gamma[l] + beta[l];
        out[(size_t)c * 128 + l + 64] =
            (v1 - mean) * rstd * gamma[l + 64] + beta[l + 64];
    }
}

extern "C" void kernel_launch(void* const* d_in, const int* in_sizes, int n_in,
                              void* d_out, int out_size, void* d_ws, size_t ws_size,
                              hipStream_t stream) {
    const float* H = (const float*)d_in[0];
    const int* ei = (const int*)d_in[1];
    const float* W = (const float*)d_in[3];
    const float* bias = (const float*)d_in[4];
    const float* gamma = (const float*)d_in[5];
    const float* beta = (const float*)d_in[6];
    float* out = (float*)d_out;

    const int N = in_sizes[0] / DFEAT;  // 10000 (<= MAXN)
    const int E = in_sizes[1] / 2;      // 640000
    const int Epb = (E + NBLK - 1) / NBLK;  // 5000 (< 65536 for u16 ranks)

    char* wp = (char*)d_ws;
    auto alloc = [&](size_t bytes) {
        char* p = wp;
        wp += (bytes + 255) & ~(size_t)255;
        return p;
    };
    int* packedHist = (int*)alloc((size_t)NBLK * N * 4);             // 5.12 MB
    unsigned short* rank16 = (unsigned short*)alloc((size_t)E * 2);  // 1.28 MB
    unsigned short* edge_src = (unsigned short*)alloc((size_t)N * PAD * 2);  // 3.2 MB
    unsigned* HsU = (unsigned*)alloc((size_t)N * (DFEAT / 2) * 4);   // 2.56 MB
    unsigned* WbT = (unsigned*)alloc((size_t)128 * (DFEAT / 2) * 4); // 32 KB
    int* cnt = (int*)alloc((size_t)N * 4);
    float* dinv = (float*)alloc((size_t)N * 4);
    (void)ws_size;

    hist_pack_kernel<<<NBLK, 1024, 0, stream>>>(ei, E, Epb, N, W,
                                                packedHist, rank16, WbT);
    colscan_kernel<<<(N * SPLIT + 255) / 256, 256, 0, stream>>>(
        packedHist, dinv, cnt, N);
    {
        int subPerBlk = 8;  // grid = 1024 blocks
        fillscale_kernel<<<NBLK * subPerBlk, 256, 0, stream>>>(
            ei, E, Epb, N, packedHist, rank16, edge_src, H, dinv, HsU, subPerBlk);
    }
    aggmmln_kernel<<<(N + 3) / 4, 256, 0, stream>>>(
        HsU, WbT, cnt, edge_src, bias, gamma, beta, out, N);
}